// Round 1
// baseline (64.022 us; speedup 1.0000x reference)
//
#include <hip/hip_runtime.h>
#include <math.h>

#define H_DIM 128
#define W_DIM 128
#define BATCH 8
#define NPIX (H_DIM * W_DIM)
#define INF_I (1 << 28)

__global__ __launch_bounds__(256) void dist_transform_kernel(
    const float* __restrict__ fm, float* __restrict__ out) {
    const int i = blockIdx.x;        // output row this block computes
    const int tid = threadIdx.x;     // 0..255

    __shared__ unsigned char maskS[NPIX];  // 16 KB boundary mask
    __shared__ int gS[W_DIM];              // column-pass result for row i
    __shared__ float distS[W_DIM];         // final distances for row i

    // ---- Pass A: mask[h][w] = any_b (fm[b][h][w] > 0.5) ----
    // Coalesced float4 loads; 16 chunks x 256 threads x 4 pixels = 16384 pixels.
    const float4* fm4 = (const float4*)fm;   // 4096 float4 per image
    #pragma unroll 2
    for (int q = 0; q < 16; ++q) {
        const int idx4 = q * 256 + tid;      // float4 index within one image
        bool m0 = false, m1 = false, m2 = false, m3 = false;
        #pragma unroll
        for (int b = 0; b < BATCH; ++b) {
            float4 v = fm4[b * 4096 + idx4];
            m0 |= v.x > 0.5f;
            m1 |= v.y > 0.5f;
            m2 |= v.z > 0.5f;
            m3 |= v.w > 0.5f;
        }
        uchar4 mm;
        mm.x = (unsigned char)m0;
        mm.y = (unsigned char)m1;
        mm.z = (unsigned char)m2;
        mm.w = (unsigned char)m3;
        ((uchar4*)maskS)[idx4] = mm;
    }
    __syncthreads();

    // ---- Pass B: column DT. g[w] = min_h (mask[h][w] ? (i-h)^2 : INF) ----
    if (tid < W_DIM) {
        const int w = tid;
        int g = INF_I;
        for (int h = 0; h < H_DIM; ++h) {
            const int d = i - h;
            const int dd = d * d;
            if (maskS[h * W_DIM + w]) g = min(g, dd);
        }
        gS[w] = g;
    }
    __syncthreads();

    // ---- Pass C: row DT. dist[j] = sqrt(min_w (g[w] + (j-w)^2)) ----
    if (tid < W_DIM) {
        const int j = tid;
        int best = INF_I;
        for (int w = 0; w < W_DIM; ++w) {
            const int d = j - w;
            best = min(best, gS[w] + d * d);
        }
        distS[j] = (best >= INF_I) ? INFINITY : sqrtf((float)best);
    }
    __syncthreads();

    // ---- Write: broadcast row i across 8 batch elements, coalesced ----
    const int j = tid & 127;
    const int bh = tid >> 7;           // 0 or 1: handles batches 0-3 / 4-7
    const float v = distS[j];
    #pragma unroll
    for (int k = 0; k < 4; ++k) {
        const int b = bh * 4 + k;
        out[b * NPIX + i * W_DIM + j] = v;
    }
}

extern "C" void kernel_launch(void* const* d_in, const int* in_sizes, int n_in,
                              void* d_out, int out_size, void* d_ws, size_t ws_size,
                              hipStream_t stream) {
    const float* fm = (const float*)d_in[0];
    float* out = (float*)d_out;
    dist_transform_kernel<<<H_DIM, 256, 0, stream>>>(fm, out);
}

// Round 2
// 57.943 us; speedup vs baseline: 1.1049x; 1.1049x over previous
//
#include <hip/hip_runtime.h>
#include <math.h>

#define H_DIM 128
#define W_DIM 128
#define BATCH 8
#define NPIX (H_DIM * W_DIM)
#define INF_I (1 << 28)

// K1: boundary mask, unioned over batch. Reads the 512 KB input exactly once.
// 16 blocks x 256 threads; each thread handles one float4 (4 pixels) across 8 batches.
__global__ __launch_bounds__(256) void mask_kernel(const float* __restrict__ fm,
                                                   unsigned char* __restrict__ mask) {
    const int idx4 = blockIdx.x * 256 + threadIdx.x;   // 0..4095 float4 within one image
    const float4* fm4 = (const float4*)fm;             // 4096 float4 per image
    bool m0 = false, m1 = false, m2 = false, m3 = false;
    #pragma unroll
    for (int b = 0; b < BATCH; ++b) {
        float4 v = fm4[b * 4096 + idx4];
        m0 |= v.x > 0.5f;
        m1 |= v.y > 0.5f;
        m2 |= v.z > 0.5f;
        m3 |= v.w > 0.5f;
    }
    uchar4 mm;
    mm.x = (unsigned char)m0;
    mm.y = (unsigned char)m1;
    mm.z = (unsigned char)m2;
    mm.w = (unsigned char)m3;
    ((uchar4*)mask)[idx4] = mm;
}

// K2: separable distance transform. One block per output row i.
// Both 128-iteration passes are split across the two 128-thread halves.
__global__ __launch_bounds__(256) void dt_kernel(const unsigned char* __restrict__ mask,
                                                 float* __restrict__ out) {
    const int i = blockIdx.x;        // output row
    const int tid = threadIdx.x;     // 0..255

    __shared__ unsigned char maskS[NPIX];   // 16 KB
    __shared__ int gpart[2][W_DIM];
    __shared__ int gS[W_DIM];
    __shared__ int bpart[2][W_DIM];
    __shared__ float distS[W_DIM];

    // Load mask 16 KB -> LDS (L2-resident after K1): 4 x 4 KB coalesced float4.
    const float4* m4 = (const float4*)mask;
    #pragma unroll
    for (int q = 0; q < 4; ++q)
        ((float4*)maskS)[q * 256 + tid] = m4[q * 256 + tid];
    __syncthreads();

    const int w = tid & 127;
    const int half = tid >> 7;       // 0: h/w in [0,64), 1: [64,128)

    // Pass B: column DT. g[w] = min_h (mask[h][w] ? (i-h)^2 : INF), h-range split.
    {
        int g = INF_I;
        const int h0 = half * 64;
        #pragma unroll 4
        for (int hh = 0; hh < 64; ++hh) {
            const int h = h0 + hh;
            const int d = i - h;
            if (maskS[h * W_DIM + w]) g = min(g, d * d);
        }
        gpart[half][w] = g;
    }
    __syncthreads();
    if (tid < W_DIM) gS[tid] = min(gpart[0][tid], gpart[1][tid]);
    __syncthreads();

    // Pass C: row DT. best[j] = min_w (g[w] + (j-w)^2), w-range split.
    {
        const int j = w;
        int best = INF_I;
        const int w0 = half * 64;
        #pragma unroll 4
        for (int ww = 0; ww < 64; ++ww) {
            const int wc = w0 + ww;
            const int d = j - wc;
            best = min(best, gS[wc] + d * d);   // max = 2^28 + 16129, no overflow
        }
        bpart[half][j] = best;
    }
    __syncthreads();
    if (tid < W_DIM) {
        const int best = min(bpart[0][tid], bpart[1][tid]);
        distS[tid] = (best >= INF_I) ? INFINITY : sqrtf((float)best);
    }
    __syncthreads();

    // Write row i broadcast across 8 batch images, coalesced.
    const int j = tid & 127;
    const int bh = tid >> 7;
    const float v = distS[j];
    #pragma unroll
    for (int k = 0; k < 4; ++k) {
        const int b = bh * 4 + k;
        out[b * NPIX + i * W_DIM + j] = v;
    }
}

extern "C" void kernel_launch(void* const* d_in, const int* in_sizes, int n_in,
                              void* d_out, int out_size, void* d_ws, size_t ws_size,
                              hipStream_t stream) {
    const float* fm = (const float*)d_in[0];
    float* out = (float*)d_out;
    unsigned char* mask = (unsigned char*)d_ws;   // 16 KB of the 256 MB workspace

    mask_kernel<<<16, 256, 0, stream>>>(fm, mask);
    dt_kernel<<<H_DIM, 256, 0, stream>>>(mask, out);
}